// Round 1
// baseline (49955.933 us; speedup 1.0000x reference)
//
#include <hip/hip_runtime.h>
#include <hip/hip_bf16.h>

// Problem constants (B=4, L=2048, D=1024, H=4096, E=8, K=2)
#define NTOK   8192
#define DDIM   1024
#define HDIM   4096
#define NEXP   8
#define CAP    8192     // max tokens per expert (a token selects an expert at most once)
#define TM     16       // tokens per FFN block
#define HCHUNK 64       // H columns per chunk
#define XPAD   1028     // bf16 elements per xs row in LDS (pad breaks 4-way bank conflict)
#define HPAD   68       // fp32 elements per h row in LDS (pad breaks same-bank stride-64)

// ---------------- Router: logits -> top2 -> softmax -> expert lists ----------------
__global__ __launch_bounds__(64) void router_kernel(
    const float* __restrict__ xs, const float* __restrict__ gw,
    int* __restrict__ counts, int* __restrict__ toklist, float* __restrict__ wglist)
{
    const int n = blockIdx.x;
    const int lane = threadIdx.x;
    const float* xrow = xs + (size_t)n * DDIM;
    float xv[16];
#pragma unroll
    for (int j = 0; j < 16; ++j) xv[j] = xrow[lane + 64 * j];
    float logit[NEXP];
#pragma unroll
    for (int e = 0; e < NEXP; ++e) {
        float p = 0.f;
        const float* gr = gw + e * DDIM;
#pragma unroll
        for (int j = 0; j < 16; ++j) p += xv[j] * gr[lane + 64 * j];
        // 64-lane butterfly reduce
#pragma unroll
        for (int off = 32; off >= 1; off >>= 1) p += __shfl_xor(p, off);
        logit[e] = p;
    }
    if (lane == 0) {
        // top-2, first-index wins ties (matches jax top_k)
        int i0 = 0;
#pragma unroll
        for (int e = 1; e < NEXP; ++e) if (logit[e] > logit[i0]) i0 = e;
        int i1 = (i0 == 0) ? 1 : 0;
#pragma unroll
        for (int e = 0; e < NEXP; ++e) if (e != i0 && logit[e] > logit[i1]) i1 = e;
        float ex = expf(logit[i1] - logit[i0]);   // <= 1
        float w0 = 1.f / (1.f + ex);
        float w1 = ex * w0;
        int p0 = atomicAdd(&counts[i0], 1);
        toklist[i0 * CAP + p0] = n;
        wglist[i0 * CAP + p0] = w0;
        int p1 = atomicAdd(&counts[i1], 1);
        toklist[i1 * CAP + p1] = n;
        wglist[i1 * CAP + p1] = w1;
    }
}

// ---------------- Fused expert FFN: out[tok] += w * relu(x@w1[e]) @ w2[e] ----------------
// Block: 256 threads, TM=16 tokens of one expert, full D=1024 output.
// H processed in chunks of 64; h chunk lives in LDS between the two phases.
__global__ __launch_bounds__(256) void ffn_kernel(
    const float* __restrict__ xs, const float* __restrict__ w1,
    const float* __restrict__ w2, const int* __restrict__ counts,
    const int* __restrict__ toklist, const float* __restrict__ wglist,
    float* __restrict__ out)
{
    const int e    = blockIdx.x >> 9;       // 512 tiles per expert
    const int tile = blockIdx.x & 511;
    const int cnt  = counts[e];
    const int m0   = tile * TM;
    if (m0 >= cnt) return;                   // uniform early-exit
    const int nt = min(TM, cnt - m0);

    __shared__ __hip_bfloat16 xs_s[TM * XPAD];        // ~32.1 KB
    __shared__ __align__(16) float h_s[TM * HPAD];    // ~4.3 KB
    __shared__ int   tok_s[TM];
    __shared__ float wg_s[TM];

    const int tid = threadIdx.x;
    if (tid < TM) {
        tok_s[tid] = (tid < nt) ? toklist[e * CAP + m0 + tid] : 0;
        wg_s[tid]  = (tid < nt) ? wglist[e * CAP + m0 + tid] : 0.f;
    }
    __syncthreads();
    // stage X tile (coalesced), zero-pad ragged rows
    for (int idx = tid; idx < TM * DDIM; idx += 256) {
        int t = idx >> 10, d = idx & (DDIM - 1);
        float v = (t < nt) ? xs[(size_t)tok_s[t] * DDIM + d] : 0.f;
        xs_s[t * XPAD + d] = __float2bfloat16(v);
    }

    float4 acc[16];                          // 64 fp32 accumulators: d = 64*j + 4*dgrp + i
#pragma unroll
    for (int j = 0; j < 16; ++j) acc[j] = make_float4(0.f, 0.f, 0.f, 0.f);

    const int hq   = tid & 15;               // phase1: h columns 4hq..4hq+3
    const int t1   = tid >> 4;               // token (both phases)
    const int dgrp = tid & 15;               // phase2 d group

    __syncthreads();

    for (int hc = 0; hc < HDIM; hc += HCHUNK) {
        // ---- phase 1: h[t1][4hq..4hq+3] = relu(x[t1] . w1[:, hc+4hq..]) ----
        const float4* w1p = reinterpret_cast<const float4*>(
            w1 + (size_t)e * DDIM * HDIM + hc) + hq;
        const __hip_bfloat16* xr = xs_s + t1 * XPAD;
        float4 s = make_float4(0.f, 0.f, 0.f, 0.f);
#pragma unroll 8
        for (int d = 0; d < DDIM; ++d) {
            float4 wv = w1p[(size_t)d * (HDIM / 4)];
            float xv = __bfloat162float(xr[d]);
            s.x += wv.x * xv; s.y += wv.y * xv;
            s.z += wv.z * xv; s.w += wv.w * xv;
        }
        s.x = fmaxf(s.x, 0.f); s.y = fmaxf(s.y, 0.f);
        s.z = fmaxf(s.z, 0.f); s.w = fmaxf(s.w, 0.f);
        *reinterpret_cast<float4*>(&h_s[t1 * HPAD + 4 * hq]) = s;
        __syncthreads();

        // ---- phase 2: acc += h[t1][k] * w2[hc+k][d] ----
        const float* w2base = w2 + ((size_t)e * HDIM + hc) * DDIM + 4 * dgrp;
        for (int k = 0; k < HCHUNK; ++k) {
            float hv = h_s[t1 * HPAD + k];
            const float4* wrow = reinterpret_cast<const float4*>(w2base + (size_t)k * DDIM);
#pragma unroll
            for (int j = 0; j < 16; ++j) {
                float4 wv = wrow[j * 16];
                acc[j].x += hv * wv.x; acc[j].y += hv * wv.y;
                acc[j].z += hv * wv.z; acc[j].w += hv * wv.w;
            }
        }
        __syncthreads();
    }

    if (t1 < nt) {
        float w = wg_s[t1];
        float* orow = out + (size_t)tok_s[t1] * DDIM;
#pragma unroll
        for (int j = 0; j < 16; ++j) {
            int d = 64 * j + 4 * dgrp;
            atomicAdd(&orow[d + 0], w * acc[j].x);
            atomicAdd(&orow[d + 1], w * acc[j].y);
            atomicAdd(&orow[d + 2], w * acc[j].z);
            atomicAdd(&orow[d + 3], w * acc[j].w);
        }
    }
}

extern "C" void kernel_launch(void* const* d_in, const int* in_sizes, int n_in,
                              void* d_out, int out_size, void* d_ws, size_t ws_size,
                              hipStream_t stream)
{
    const float* xs = (const float*)d_in[0];   // (B,L,D) fp32
    const float* gw = (const float*)d_in[1];   // (E,D)
    const float* w1 = (const float*)d_in[2];   // (E,D,H)
    const float* w2 = (const float*)d_in[3];   // (E,H,D)
    float* out = (float*)d_out;                // (B,L,D) fp32

    char* ws = (char*)d_ws;
    int*   counts  = (int*)ws;                            // 8 ints (zeroed below)
    int*   toklist = (int*)(ws + 1024);                   // E*CAP ints   (256 KB)
    float* wglist  = (float*)(ws + 1024 + NEXP * CAP * 4);// E*CAP floats (256 KB)

    hipMemsetAsync(counts, 0, 1024, stream);
    hipMemsetAsync(d_out, 0, (size_t)out_size * sizeof(float), stream);

    router_kernel<<<NTOK, 64, 0, stream>>>(xs, gw, counts, toklist, wglist);
    ffn_kernel<<<NEXP * (CAP / TM), 256, 0, stream>>>(xs, w1, w2, counts, toklist, wglist, out);
}

// Round 2
// 1117.910 us; speedup vs baseline: 44.6869x; 44.6869x over previous
//
#include <hip/hip_runtime.h>
#include <hip/hip_bf16.h>

// Problem constants (B=4, L=2048, D=1024, H=4096, E=8, K=2)
#define NTOK   8192
#define DDIM   1024
#define HDIM   4096
#define NEXP   8
#define CAP    8192
#define NSLOT  (NTOK * 2)    // total (token, expert) pairs = N*K

// GEMM tiling
#define BM 128
#define BN 128
#define BK 64
#define KPAD 72              // LDS row stride in bf16 elems (pad kills stride-128B bank pattern)

typedef __attribute__((ext_vector_type(8))) short bf16x8;
typedef __attribute__((ext_vector_type(4))) float f32x4;

// ---------------- Router: logits -> top2 -> softmax -> expert lists ----------------
__global__ __launch_bounds__(64) void router_kernel(
    const float* __restrict__ xs, const float* __restrict__ gw,
    int* __restrict__ counts, int* __restrict__ toklist, float* __restrict__ wglist)
{
    const int n = blockIdx.x;
    const int lane = threadIdx.x;
    const float* xrow = xs + (size_t)n * DDIM;
    float xv[16];
#pragma unroll
    for (int j = 0; j < 16; ++j) xv[j] = xrow[lane + 64 * j];
    float logit[NEXP];
#pragma unroll
    for (int e = 0; e < NEXP; ++e) {
        float p = 0.f;
        const float* gr = gw + e * DDIM;
#pragma unroll
        for (int j = 0; j < 16; ++j) p += xv[j] * gr[lane + 64 * j];
#pragma unroll
        for (int off = 32; off >= 1; off >>= 1) p += __shfl_xor(p, off);
        logit[e] = p;
    }
    if (lane == 0) {
        int i0 = 0;
#pragma unroll
        for (int e = 1; e < NEXP; ++e) if (logit[e] > logit[i0]) i0 = e;
        int i1 = (i0 == 0) ? 1 : 0;
#pragma unroll
        for (int e = 0; e < NEXP; ++e) if (e != i0 && logit[e] > logit[i1]) i1 = e;
        float ex = expf(logit[i1] - logit[i0]);
        float w0 = 1.f / (1.f + ex);
        float w1 = ex * w0;
        int p0 = atomicAdd(&counts[i0], 1);
        toklist[i0 * CAP + p0] = n;
        wglist[i0 * CAP + p0] = w0;
        int p1 = atomicAdd(&counts[i1], 1);
        toklist[i1 * CAP + p1] = n;
        wglist[i1 * CAP + p1] = w1;
    }
}

__global__ void prefix_kernel(const int* __restrict__ counts, int* __restrict__ base)
{
    if (threadIdx.x == 0 && blockIdx.x == 0) {
        int s = 0;
        for (int e = 0; e < NEXP; ++e) { base[e] = s; s += counts[e]; }
    }
}

// ---------------- xs fp32 -> bf16 ----------------
__global__ __launch_bounds__(256) void cvt_xs_kernel(
    const float* __restrict__ xs, __hip_bfloat16* __restrict__ xsb)
{
    const size_t i = ((size_t)blockIdx.x * 256 + threadIdx.x) * 8;
    const float4 a = *(const float4*)(xs + i);
    const float4 b = *(const float4*)(xs + i + 4);
    __hip_bfloat16 o[8];
    o[0] = __float2bfloat16(a.x); o[1] = __float2bfloat16(a.y);
    o[2] = __float2bfloat16(a.z); o[3] = __float2bfloat16(a.w);
    o[4] = __float2bfloat16(b.x); o[5] = __float2bfloat16(b.y);
    o[6] = __float2bfloat16(b.z); o[7] = __float2bfloat16(b.w);
    *(bf16x8*)(xsb + i) = *(bf16x8*)o;
}

// ---------------- per-expert transpose fp32 (RxC) -> bf16 (CxR) ----------------
__global__ __launch_bounds__(256) void transpose_bf16_kernel(
    const float* __restrict__ src, __hip_bfloat16* __restrict__ dst, int R, int C)
{
    __shared__ __hip_bfloat16 t[64][65];
    const int e = blockIdx.z;
    src += (size_t)e * R * C;
    dst += (size_t)e * R * C;
    const int r0 = blockIdx.y * 64, c0 = blockIdx.x * 64;
    const int tid = threadIdx.x;
#pragma unroll
    for (int i = 0; i < 16; ++i) {
        int lin = tid + 256 * i;
        int r = lin >> 6, c = lin & 63;
        t[r][c] = __float2bfloat16(src[(size_t)(r0 + r) * C + c0 + c]);
    }
    __syncthreads();
#pragma unroll
    for (int i = 0; i < 16; ++i) {
        int lin = tid + 256 * i;
        int c = lin >> 6, r = lin & 63;
        dst[(size_t)(c0 + c) * R + r0 + r] = t[r][c];
    }
}

// ---------------- GEMM1: h[slot][:] = relu(x[tok] @ w1[e]), bf16 out ----------------
// A = xsb gathered rows (M=cnt x K=1024), B = w1t[e] (N=4096 rows x K), both K-contiguous.
__global__ __launch_bounds__(256) void gemm1_kernel(
    const __hip_bfloat16* __restrict__ xsb, const __hip_bfloat16* __restrict__ w1t,
    const int* __restrict__ counts, const int* __restrict__ base,
    const int* __restrict__ toklist, __hip_bfloat16* __restrict__ h)
{
    const int e = blockIdx.z;
    const int cnt = counts[e];
    const int m0 = blockIdx.y * BM;
    if (m0 >= cnt) return;
    const int n0 = blockIdx.x * BN;

    __shared__ __align__(16) __hip_bfloat16 As[BM * KPAD];
    __shared__ __align__(16) __hip_bfloat16 Bs[BN * KPAD];
    __shared__ int tok_s[BM];

    const int tid = threadIdx.x;
    if (tid < BM) {
        int m = m0 + tid;
        tok_s[tid] = (m < cnt) ? toklist[e * CAP + m] : -1;
    }
    __syncthreads();

    f32x4 acc[4][4];
#pragma unroll
    for (int i = 0; i < 4; ++i)
#pragma unroll
        for (int j = 0; j < 4; ++j) acc[i][j] = (f32x4){0.f, 0.f, 0.f, 0.f};

    const int wave = tid >> 6;
    const int lane = tid & 63;
    const int wm = (wave >> 1) * 64;
    const int wn = (wave & 1) * 64;
    const int l15 = lane & 15;
    const int quad = lane >> 4;
    const int srow = tid >> 3;            // 0..31
    const int soct = (tid & 7) * 8;       // k offset (elems)
    const __hip_bfloat16* w1e = w1t + (size_t)e * HDIM * DDIM;

    for (int k0 = 0; k0 < DDIM; k0 += BK) {
#pragma unroll
        for (int rr = 0; rr < 4; ++rr) {
            int m = srow + rr * 32;
            int t = tok_s[m];
            bf16x8 v = {0, 0, 0, 0, 0, 0, 0, 0};
            if (t >= 0) v = *(const bf16x8*)(xsb + (size_t)t * DDIM + k0 + soct);
            *(bf16x8*)(As + m * KPAD + soct) = v;
        }
#pragma unroll
        for (int rr = 0; rr < 4; ++rr) {
            int n = srow + rr * 32;
            bf16x8 v = *(const bf16x8*)(w1e + (size_t)(n0 + n) * DDIM + k0 + soct);
            *(bf16x8*)(Bs + n * KPAD + soct) = v;
        }
        __syncthreads();
#pragma unroll
        for (int kk = 0; kk < 2; ++kk) {
            bf16x8 a[4], b[4];
#pragma unroll
            for (int i = 0; i < 4; ++i)
                a[i] = *(const bf16x8*)(As + (wm + i * 16 + l15) * KPAD + kk * 32 + quad * 8);
#pragma unroll
            for (int j = 0; j < 4; ++j)
                b[j] = *(const bf16x8*)(Bs + (wn + j * 16 + l15) * KPAD + kk * 32 + quad * 8);
#pragma unroll
            for (int i = 0; i < 4; ++i)
#pragma unroll
                for (int j = 0; j < 4; ++j)
                    acc[i][j] = __builtin_amdgcn_mfma_f32_16x16x32_bf16(a[i], b[j], acc[i][j], 0, 0, 0);
        }
        __syncthreads();
    }

    const int slot0 = base[e] + m0;
#pragma unroll
    for (int i = 0; i < 4; ++i) {
#pragma unroll
        for (int r = 0; r < 4; ++r) {
            int row = wm + i * 16 + quad * 4 + r;
            if (m0 + row < cnt) {
                size_t hrow = (size_t)(slot0 + row) * HDIM + n0 + wn;
#pragma unroll
                for (int j = 0; j < 4; ++j)
                    h[hrow + j * 16 + l15] = __float2bfloat16(fmaxf(acc[i][j][r], 0.f));
            }
        }
    }
}

// ---------------- GEMM2: out[tok][:] += w * (h[slot] @ w2[e]) ----------------
__global__ __launch_bounds__(256) void gemm2_kernel(
    const __hip_bfloat16* __restrict__ h, const __hip_bfloat16* __restrict__ w2t,
    const int* __restrict__ counts, const int* __restrict__ base,
    const int* __restrict__ toklist, const float* __restrict__ wglist,
    float* __restrict__ out)
{
    const int e = blockIdx.z;
    const int cnt = counts[e];
    const int m0 = blockIdx.y * BM;
    if (m0 >= cnt) return;
    const int n0 = blockIdx.x * BN;

    __shared__ __align__(16) __hip_bfloat16 As[BM * KPAD];
    __shared__ __align__(16) __hip_bfloat16 Bs[BN * KPAD];
    __shared__ int   tok_s[BM];
    __shared__ float wg_s[BM];

    const int tid = threadIdx.x;
    if (tid < BM) {
        int m = m0 + tid;
        tok_s[tid] = (m < cnt) ? toklist[e * CAP + m] : -1;
        wg_s[tid]  = (m < cnt) ? wglist[e * CAP + m] : 0.f;
    }
    __syncthreads();

    f32x4 acc[4][4];
#pragma unroll
    for (int i = 0; i < 4; ++i)
#pragma unroll
        for (int j = 0; j < 4; ++j) acc[i][j] = (f32x4){0.f, 0.f, 0.f, 0.f};

    const int wave = tid >> 6;
    const int lane = tid & 63;
    const int wm = (wave >> 1) * 64;
    const int wn = (wave & 1) * 64;
    const int l15 = lane & 15;
    const int quad = lane >> 4;
    const int srow = tid >> 3;
    const int soct = (tid & 7) * 8;
    const int slot0 = base[e] + m0;
    const __hip_bfloat16* w2e = w2t + (size_t)e * DDIM * HDIM;

    for (int k0 = 0; k0 < HDIM; k0 += BK) {
#pragma unroll
        for (int rr = 0; rr < 4; ++rr) {
            int m = srow + rr * 32;
            bf16x8 v = {0, 0, 0, 0, 0, 0, 0, 0};
            if (m0 + m < cnt) v = *(const bf16x8*)(h + (size_t)(slot0 + m) * HDIM + k0 + soct);
            *(bf16x8*)(As + m * KPAD + soct) = v;
        }
#pragma unroll
        for (int rr = 0; rr < 4; ++rr) {
            int n = srow + rr * 32;
            bf16x8 v = *(const bf16x8*)(w2e + (size_t)(n0 + n) * HDIM + k0 + soct);
            *(bf16x8*)(Bs + n * KPAD + soct) = v;
        }
        __syncthreads();
#pragma unroll
        for (int kk = 0; kk < 2; ++kk) {
            bf16x8 a[4], b[4];
#pragma unroll
            for (int i = 0; i < 4; ++i)
                a[i] = *(const bf16x8*)(As + (wm + i * 16 + l15) * KPAD + kk * 32 + quad * 8);
#pragma unroll
            for (int j = 0; j < 4; ++j)
                b[j] = *(const bf16x8*)(Bs + (wn + j * 16 + l15) * KPAD + kk * 32 + quad * 8);
#pragma unroll
            for (int i = 0; i < 4; ++i)
#pragma unroll
                for (int j = 0; j < 4; ++j)
                    acc[i][j] = __builtin_amdgcn_mfma_f32_16x16x32_bf16(a[i], b[j], acc[i][j], 0, 0, 0);
        }
        __syncthreads();
    }

#pragma unroll
    for (int i = 0; i < 4; ++i) {
#pragma unroll
        for (int r = 0; r < 4; ++r) {
            int row = wm + i * 16 + quad * 4 + r;
            if (m0 + row < cnt) {
                int tok = tok_s[row];
                float w = wg_s[row];
                float* orow = out + (size_t)tok * DDIM + n0 + wn;
#pragma unroll
                for (int j = 0; j < 4; ++j)
                    atomicAdd(&orow[j * 16 + l15], w * acc[i][j][r]);
            }
        }
    }
}

extern "C" void kernel_launch(void* const* d_in, const int* in_sizes, int n_in,
                              void* d_out, int out_size, void* d_ws, size_t ws_size,
                              hipStream_t stream)
{
    const float* xs = (const float*)d_in[0];   // (B,L,D) fp32
    const float* gw = (const float*)d_in[1];   // (E,D)
    const float* w1 = (const float*)d_in[2];   // (E,D,H)
    const float* w2 = (const float*)d_in[3];   // (E,H,D)
    float* out = (float*)d_out;

    char* ws = (char*)d_ws;
    size_t o = 0;
    int*   counts  = (int*)(ws + o);  o += 256;
    int*   base    = (int*)(ws + o);  o += 256;
    int*   toklist = (int*)(ws + o);  o += (size_t)NEXP * CAP * 4;
    float* wglist  = (float*)(ws + o); o += (size_t)NEXP * CAP * 4;
    __hip_bfloat16* xsb = (__hip_bfloat16*)(ws + o); o += (size_t)NTOK * DDIM * 2;
    __hip_bfloat16* w1t = (__hip_bfloat16*)(ws + o); o += (size_t)NEXP * DDIM * HDIM * 2;
    __hip_bfloat16* w2t = (__hip_bfloat16*)(ws + o); o += (size_t)NEXP * DDIM * HDIM * 2;
    __hip_bfloat16* hbuf = (__hip_bfloat16*)(ws + o); o += (size_t)NSLOT * HDIM * 2;

    hipMemsetAsync(counts, 0, 256, stream);
    hipMemsetAsync(d_out, 0, (size_t)out_size * sizeof(float), stream);

    router_kernel<<<NTOK, 64, 0, stream>>>(xs, gw, counts, toklist, wglist);
    prefix_kernel<<<1, 64, 0, stream>>>(counts, base);
    cvt_xs_kernel<<<(NTOK * DDIM) / (256 * 8), 256, 0, stream>>>(xs, xsb);
    transpose_bf16_kernel<<<dim3(HDIM / 64, DDIM / 64, NEXP), 256, 0, stream>>>(w1, w1t, DDIM, HDIM);
    transpose_bf16_kernel<<<dim3(DDIM / 64, HDIM / 64, NEXP), 256, 0, stream>>>(w2, w2t, HDIM, DDIM);

    gemm1_kernel<<<dim3(HDIM / BN, CAP / BM, NEXP), 256, 0, stream>>>(
        xsb, w1t, counts, base, toklist, hbuf);
    gemm2_kernel<<<dim3(DDIM / BN, CAP / BM, NEXP), 256, 0, stream>>>(
        hbuf, w2t, counts, base, toklist, wglist, out);
}

// Round 3
// 1098.433 us; speedup vs baseline: 45.4793x; 1.0177x over previous
//
#include <hip/hip_runtime.h>
#include <hip/hip_bf16.h>

// Problem constants (B=4, L=2048, D=1024, H=4096, E=8, K=2)
#define NTOK   8192
#define DDIM   1024
#define HDIM   4096
#define NEXP   8
#define CAP    8192
#define NSLOT  (NTOK * 2)

// GEMM tiling (m97 structure: unpadded LDS, global_load_lds width-16 staging)
#define BM 128
#define BN 128
#define BK 64

typedef __attribute__((ext_vector_type(8))) short bf16x8;
typedef __attribute__((ext_vector_type(4))) float f32x4;

// async global->LDS, 16B per lane; LDS dest = wave-uniform base + lane*16
#define GLD16(g, l) __builtin_amdgcn_global_load_lds(                          \
    (const __attribute__((address_space(1))) void*)(g),                        \
    (__attribute__((address_space(3))) void*)(l), 16, 0, 0)

// ---------------- Router: logits -> top2 -> softmax -> expert lists ----------------
__global__ __launch_bounds__(64) void router_kernel(
    const float* __restrict__ xs, const float* __restrict__ gw,
    int* __restrict__ counts, int* __restrict__ toklist, float* __restrict__ wglist)
{
    const int n = blockIdx.x;
    const int lane = threadIdx.x;
    const float* xrow = xs + (size_t)n * DDIM;
    float xv[16];
#pragma unroll
    for (int j = 0; j < 16; ++j) xv[j] = xrow[lane + 64 * j];
    float logit[NEXP];
#pragma unroll
    for (int e = 0; e < NEXP; ++e) {
        float p = 0.f;
        const float* gr = gw + e * DDIM;
#pragma unroll
        for (int j = 0; j < 16; ++j) p += xv[j] * gr[lane + 64 * j];
#pragma unroll
        for (int off = 32; off >= 1; off >>= 1) p += __shfl_xor(p, off);
        logit[e] = p;
    }
    if (lane == 0) {
        int i0 = 0;
#pragma unroll
        for (int e = 1; e < NEXP; ++e) if (logit[e] > logit[i0]) i0 = e;
        int i1 = (i0 == 0) ? 1 : 0;
#pragma unroll
        for (int e = 0; e < NEXP; ++e) if (e != i0 && logit[e] > logit[i1]) i1 = e;
        float ex = expf(logit[i1] - logit[i0]);
        float w0 = 1.f / (1.f + ex);
        float w1 = ex * w0;
        int p0 = atomicAdd(&counts[i0], 1);
        toklist[i0 * CAP + p0] = n;
        wglist[i0 * CAP + p0] = w0;
        int p1 = atomicAdd(&counts[i1], 1);
        toklist[i1 * CAP + p1] = n;
        wglist[i1 * CAP + p1] = w1;
    }
}

__global__ void prefix_kernel(const int* __restrict__ counts, int* __restrict__ base)
{
    if (threadIdx.x == 0 && blockIdx.x == 0) {
        int s = 0;
        for (int e = 0; e < NEXP; ++e) { base[e] = s; s += counts[e]; }
    }
}

// ---------------- xs fp32 -> bf16 ----------------
__global__ __launch_bounds__(256) void cvt_xs_kernel(
    const float* __restrict__ xs, __hip_bfloat16* __restrict__ xsb)
{
    const size_t i = ((size_t)blockIdx.x * 256 + threadIdx.x) * 8;
    const float4 a = *(const float4*)(xs + i);
    const float4 b = *(const float4*)(xs + i + 4);
    __hip_bfloat16 o[8];
    o[0] = __float2bfloat16(a.x); o[1] = __float2bfloat16(a.y);
    o[2] = __float2bfloat16(a.z); o[3] = __float2bfloat16(a.w);
    o[4] = __float2bfloat16(b.x); o[5] = __float2bfloat16(b.y);
    o[6] = __float2bfloat16(b.z); o[7] = __float2bfloat16(b.w);
    *(bf16x8*)(xsb + i) = *(bf16x8*)o;
}

// ---------------- per-expert transpose fp32 (RxC) -> bf16 (CxR) ----------------
__global__ __launch_bounds__(256) void transpose_bf16_kernel(
    const float* __restrict__ src, __hip_bfloat16* __restrict__ dst, int R, int C)
{
    __shared__ __hip_bfloat16 t[64][72];
    const int e = blockIdx.z;
    src += (size_t)e * R * C;
    dst += (size_t)e * R * C;
    const int r0 = blockIdx.y * 64, c0 = blockIdx.x * 64;
    const int tid = threadIdx.x;
#pragma unroll
    for (int i = 0; i < 4; ++i) {
        int r = (tid >> 4) + 16 * i;
        int c = (tid & 15) * 4;
        float4 v = *(const float4*)(src + (size_t)(r0 + r) * C + c0 + c);
        t[r][c + 0] = __float2bfloat16(v.x);
        t[r][c + 1] = __float2bfloat16(v.y);
        t[r][c + 2] = __float2bfloat16(v.z);
        t[r][c + 3] = __float2bfloat16(v.w);
    }
    __syncthreads();
#pragma unroll
    for (int i = 0; i < 4; ++i) {
        int c = (tid >> 4) + 16 * i;
        int r = (tid & 15) * 4;
        __hip_bfloat16 o[4] = { t[r][c], t[r + 1][c], t[r + 2][c], t[r + 3][c] };
        *(short4*)(dst + (size_t)(c0 + c) * R + r0 + r) = *(short4*)o;
    }
}

// ---------------- GEMM1: h[slot][:] = relu(x[tok] @ w1[e]), bf16 out ----------------
__global__ __launch_bounds__(256) void gemm1_kernel(
    const __hip_bfloat16* __restrict__ xsb, const __hip_bfloat16* __restrict__ w1t,
    const int* __restrict__ counts, const int* __restrict__ base,
    const int* __restrict__ toklist, __hip_bfloat16* __restrict__ h)
{
    const int e = blockIdx.z;
    const int cnt = counts[e];
    const int m0 = blockIdx.y * BM;
    if (m0 >= cnt) return;
    const int n0 = blockIdx.x * BN;

    __shared__ __align__(16) __hip_bfloat16 As[BM * BK];
    __shared__ __align__(16) __hip_bfloat16 Bs[BN * BK];
    __shared__ int tok_s[BM];

    const int tid = threadIdx.x;
    if (tid < BM) tok_s[tid] = toklist[e * CAP + min(m0 + tid, cnt - 1)];
    __syncthreads();

    const int wave = tid >> 6;
    const int lane = tid & 63;
    const int lrow = lane >> 3;          // 0..7
    const int lcol = (lane & 7) * 8;     // k elems
    const __hip_bfloat16* w1e = w1t + (size_t)e * HDIM * DDIM;

    const __hip_bfloat16* srcA[4];
    const __hip_bfloat16* srcB[4];
#pragma unroll
    for (int c = 0; c < 4; ++c) {
        int r = wave * 32 + c * 8 + lrow;
        srcA[c] = xsb + (size_t)tok_s[r] * DDIM + lcol;
        srcB[c] = w1e + (size_t)(n0 + r) * DDIM + lcol;
    }

    f32x4 acc[4][4];
#pragma unroll
    for (int i = 0; i < 4; ++i)
#pragma unroll
        for (int j = 0; j < 4; ++j) acc[i][j] = (f32x4){0.f, 0.f, 0.f, 0.f};

    const int wm = (wave >> 1) * 64;
    const int wn = (wave & 1) * 64;
    const int l15 = lane & 15;
    const int quad = lane >> 4;

    for (int k0 = 0; k0 < DDIM; k0 += BK) {
#pragma unroll
        for (int c = 0; c < 4; ++c) {
            GLD16(srcA[c] + k0, As + (wave * 32 + c * 8) * BK);
            GLD16(srcB[c] + k0, Bs + (wave * 32 + c * 8) * BK);
        }
        __syncthreads();
#pragma unroll
        for (int kk = 0; kk < 2; ++kk) {
            bf16x8 a[4], b[4];
#pragma unroll
            for (int i = 0; i < 4; ++i)
                a[i] = *(const bf16x8*)(As + (wm + i * 16 + l15) * BK + kk * 32 + quad * 8);
#pragma unroll
            for (int j = 0; j < 4; ++j)
                b[j] = *(const bf16x8*)(Bs + (wn + j * 16 + l15) * BK + kk * 32 + quad * 8);
#pragma unroll
            for (int i = 0; i < 4; ++i)
#pragma unroll
                for (int j = 0; j < 4; ++j)
                    acc[i][j] = __builtin_amdgcn_mfma_f32_16x16x32_bf16(a[i], b[j], acc[i][j], 0, 0, 0);
        }
        __syncthreads();
    }

    const int slot0 = base[e] + m0;
#pragma unroll
    for (int i = 0; i < 4; ++i) {
#pragma unroll
        for (int r = 0; r < 4; ++r) {
            int row = wm + i * 16 + quad * 4 + r;
            if (m0 + row < cnt) {
                size_t hrow = (size_t)(slot0 + row) * HDIM + n0 + wn;
#pragma unroll
                for (int j = 0; j < 4; ++j)
                    h[hrow + j * 16 + l15] = __float2bfloat16(fmaxf(acc[i][j][r], 0.f));
            }
        }
    }
}

// ---------------- GEMM2: out[tok][:] += w * (h[slot] @ w2[e]) ----------------
__global__ __launch_bounds__(256) void gemm2_kernel(
    const __hip_bfloat16* __restrict__ h, const __hip_bfloat16* __restrict__ w2t,
    const int* __restrict__ counts, const int* __restrict__ base,
    const int* __restrict__ toklist, const float* __restrict__ wglist,
    float* __restrict__ out)
{
    const int e = blockIdx.z;
    const int cnt = counts[e];
    const int m0 = blockIdx.y * BM;
    if (m0 >= cnt) return;
    const int n0 = blockIdx.x * BN;

    __shared__ __align__(16) __hip_bfloat16 As[BM * BK];
    __shared__ __align__(16) __hip_bfloat16 Bs[BN * BK];
    __shared__ int   tok_s[BM];
    __shared__ float wg_s[BM];

    const int tid = threadIdx.x;
    if (tid < BM) {
        int m = m0 + tid;
        tok_s[tid] = (m < cnt) ? toklist[e * CAP + m] : -1;
        wg_s[tid]  = (m < cnt) ? wglist[e * CAP + m] : 0.f;
    }
    __syncthreads();

    const int wave = tid >> 6;
    const int lane = tid & 63;
    const int lrow = lane >> 3;
    const int lcol = (lane & 7) * 8;
    const int slot0 = base[e];
    const __hip_bfloat16* w2e = w2t + (size_t)e * DDIM * HDIM;

    const __hip_bfloat16* srcA[4];
    const __hip_bfloat16* srcB[4];
#pragma unroll
    for (int c = 0; c < 4; ++c) {
        int r = wave * 32 + c * 8 + lrow;
        srcA[c] = h + (size_t)(slot0 + min(m0 + r, cnt - 1)) * HDIM + lcol;
        srcB[c] = w2e + (size_t)(n0 + r) * HDIM + lcol;
    }

    f32x4 acc[4][4];
#pragma unroll
    for (int i = 0; i < 4; ++i)
#pragma unroll
        for (int j = 0; j < 4; ++j) acc[i][j] = (f32x4){0.f, 0.f, 0.f, 0.f};

    const int wm = (wave >> 1) * 64;
    const int wn = (wave & 1) * 64;
    const int l15 = lane & 15;
    const int quad = lane >> 4;

    for (int k0 = 0; k0 < HDIM; k0 += BK) {
#pragma unroll
        for (int c = 0; c < 4; ++c) {
            GLD16(srcA[c] + k0, As + (wave * 32 + c * 8) * BK);
            GLD16(srcB[c] + k0, Bs + (wave * 32 + c * 8) * BK);
        }
        __syncthreads();
#pragma unroll
        for (int kk = 0; kk < 2; ++kk) {
            bf16x8 a[4], b[4];
#pragma unroll
            for (int i = 0; i < 4; ++i)
                a[i] = *(const bf16x8*)(As + (wm + i * 16 + l15) * BK + kk * 32 + quad * 8);
#pragma unroll
            for (int j = 0; j < 4; ++j)
                b[j] = *(const bf16x8*)(Bs + (wn + j * 16 + l15) * BK + kk * 32 + quad * 8);
#pragma unroll
            for (int i = 0; i < 4; ++i)
#pragma unroll
                for (int j = 0; j < 4; ++j)
                    acc[i][j] = __builtin_amdgcn_mfma_f32_16x16x32_bf16(a[i], b[j], acc[i][j], 0, 0, 0);
        }
        __syncthreads();
    }

#pragma unroll
    for (int i = 0; i < 4; ++i) {
#pragma unroll
        for (int r = 0; r < 4; ++r) {
            int row = wm + i * 16 + quad * 4 + r;
            if (m0 + row < cnt) {
                int tok = tok_s[row];
                float w = wg_s[row];
                float* orow = out + (size_t)tok * DDIM + n0 + wn;
#pragma unroll
                for (int j = 0; j < 4; ++j)
                    atomicAdd(&orow[j * 16 + l15], w * acc[i][j][r]);
            }
        }
    }
}

extern "C" void kernel_launch(void* const* d_in, const int* in_sizes, int n_in,
                              void* d_out, int out_size, void* d_ws, size_t ws_size,
                              hipStream_t stream)
{
    const float* xs = (const float*)d_in[0];   // (B,L,D) fp32
    const float* gw = (const float*)d_in[1];   // (E,D)
    const float* w1 = (const float*)d_in[2];   // (E,D,H)
    const float* w2 = (const float*)d_in[3];   // (E,H,D)
    float* out = (float*)d_out;

    char* ws = (char*)d_ws;
    size_t o = 0;
    int*   counts  = (int*)(ws + o);  o += 256;
    int*   base    = (int*)(ws + o);  o += 256;
    int*   toklist = (int*)(ws + o);  o += (size_t)NEXP * CAP * 4;
    float* wglist  = (float*)(ws + o); o += (size_t)NEXP * CAP * 4;
    __hip_bfloat16* xsb = (__hip_bfloat16*)(ws + o); o += (size_t)NTOK * DDIM * 2;
    __hip_bfloat16* w1t = (__hip_bfloat16*)(ws + o); o += (size_t)NEXP * DDIM * HDIM * 2;
    __hip_bfloat16* w2t = (__hip_bfloat16*)(ws + o); o += (size_t)NEXP * DDIM * HDIM * 2;
    __hip_bfloat16* hbuf = (__hip_bfloat16*)(ws + o); o += (size_t)NSLOT * HDIM * 2;

    hipMemsetAsync(counts, 0, 256, stream);
    hipMemsetAsync(d_out, 0, (size_t)out_size * sizeof(float), stream);

    router_kernel<<<NTOK, 64, 0, stream>>>(xs, gw, counts, toklist, wglist);
    prefix_kernel<<<1, 64, 0, stream>>>(counts, base);
    cvt_xs_kernel<<<(NTOK * DDIM) / (256 * 8), 256, 0, stream>>>(xs, xsb);
    transpose_bf16_kernel<<<dim3(HDIM / 64, DDIM / 64, NEXP), 256, 0, stream>>>(w1, w1t, DDIM, HDIM);
    transpose_bf16_kernel<<<dim3(DDIM / 64, HDIM / 64, NEXP), 256, 0, stream>>>(w2, w2t, HDIM, DDIM);

    gemm1_kernel<<<dim3(HDIM / BN, CAP / BM, NEXP), 256, 0, stream>>>(
        xsb, w1t, counts, base, toklist, hbuf);
    gemm2_kernel<<<dim3(DDIM / BN, CAP / BM, NEXP), 256, 0, stream>>>(
        hbuf, w2t, counts, base, toklist, wglist, out);
}